// Round 1
// baseline (9356.716 us; speedup 1.0000x reference)
//
#include <hip/hip_runtime.h>
#include <hip/hip_bf16.h>
#include <math.h>

// Problem constants
#define S_LEN 2048
#define HIDDEN 4096
#define N_HEADS 32
#define N_KV 8
#define HEAD_DIM 128

// ---------------------------------------------------------------------------
// Generic fp32 GEMM:  C[M,N] = A[M,K] @ B[N,K]^T   (both row-major, K contig)
// 64x64 tile, BK=16, 16x16 threads, 4x4 per thread. M,N,K multiples of 64/16.
// ---------------------------------------------------------------------------
#define TS 64
#define BK 16

__global__ __launch_bounds__(256) void gemm_f32_bt(
    const float* __restrict__ A, const float* __restrict__ B,
    float* __restrict__ C, int M, int N, int K) {
  __shared__ float As[TS][BK + 1];
  __shared__ float Bs[TS][BK + 1];

  const int tx = threadIdx.x;  // 0..15
  const int ty = threadIdx.y;  // 0..15
  const int tid = ty * 16 + tx;
  const int blockRow = blockIdx.y * TS;
  const int blockCol = blockIdx.x * TS;

  float acc[4][4] = {};

  for (int k0 = 0; k0 < K; k0 += BK) {
    // Stage 64x16 tiles of A and B (1024 elements each, 4 per thread)
#pragma unroll
    for (int i = 0; i < 4; i++) {
      int idx = tid + i * 256;      // 0..1023
      int m = idx >> 4;             // 0..63
      int kk = idx & 15;
      As[m][kk] = A[(size_t)(blockRow + m) * K + k0 + kk];
      Bs[m][kk] = B[(size_t)(blockCol + m) * K + k0 + kk];
    }
    __syncthreads();

#pragma unroll
    for (int kk = 0; kk < BK; kk++) {
      float a[4], b[4];
#pragma unroll
      for (int i = 0; i < 4; i++) a[i] = As[ty * 4 + i][kk];
#pragma unroll
      for (int j = 0; j < 4; j++) b[j] = Bs[tx * 4 + j][kk];
#pragma unroll
      for (int i = 0; i < 4; i++)
#pragma unroll
        for (int j = 0; j < 4; j++) acc[i][j] += a[i] * b[j];
    }
    __syncthreads();
  }

#pragma unroll
  for (int i = 0; i < 4; i++)
#pragma unroll
    for (int j = 0; j < 4; j++)
      C[(size_t)(blockRow + ty * 4 + i) * N + blockCol + tx * 4 + j] = acc[i][j];
}

// ---------------------------------------------------------------------------
// RoPE applied in-place to Q [S, 32, 128] and K [S, 8, 128].
// For pair (d, d+64), d in [0,64): ang = s * 10000^(-d/64)
//   out[d]    = x1*cos - x2*sin
//   out[d+64] = x2*cos + x1*sin
// ---------------------------------------------------------------------------
__global__ void rope_kernel(float* __restrict__ Q, float* __restrict__ K) {
  int idx = blockIdx.x * blockDim.x + threadIdx.x;  // S * 40 * 64 total
  int d = idx & 63;
  int sh = idx >> 6;
  int h = sh % (N_HEADS + N_KV);
  int s = sh / (N_HEADS + N_KV);
  if (s >= S_LEN) return;

  float freq = expf(-(float)d * (9.210340371976184f / 64.0f));  // 10000^(-d/64)
  float ang = (float)s * freq;
  float sn, cs;
  sincosf(ang, &sn, &cs);

  float* ptr;
  if (h < N_HEADS)
    ptr = Q + ((size_t)s * N_HEADS + h) * HEAD_DIM;
  else
    ptr = K + ((size_t)s * N_KV + (h - N_HEADS)) * HEAD_DIM;

  float x1 = ptr[d];
  float x2 = ptr[d + 64];
  ptr[d] = x1 * cs - x2 * sn;
  ptr[d + 64] = x2 * cs + x1 * sn;
}

// ---------------------------------------------------------------------------
// Causal GQA attention, one block of 256 threads per (query row, head).
// Q [S,32,128], K/V [S,8,128], O [S,32,128] (== [S, 4096] for out proj).
// Two-pass softmax with the full score row (<= 2048 floats) in LDS.
// ---------------------------------------------------------------------------
__global__ __launch_bounds__(256) void attn_kernel(
    const float* __restrict__ Q, const float* __restrict__ Kc,
    const float* __restrict__ Vc, float* __restrict__ O) {
  const int q = blockIdx.x;
  const int h = blockIdx.y;
  const int kvh = h >> 2;  // 32 heads -> 8 kv heads, groups of 4
  const int tid = threadIdx.x;

  __shared__ float sc[S_LEN];
  __shared__ float qv[HEAD_DIM];
  __shared__ float red[4];
  __shared__ float out2[HEAD_DIM];

  if (tid < HEAD_DIM) qv[tid] = Q[((size_t)q * N_HEADS + h) * HEAD_DIM + tid];
  __syncthreads();

  const int L = q + 1;
  const float scale = 0.08838834764831845f;  // 1/sqrt(128)

  // Pass 1: scores + local max
  float lmax = -1e30f;
  for (int k = tid; k < L; k += 256) {
    const float* kp = Kc + ((size_t)k * N_KV + kvh) * HEAD_DIM;
    float dot = 0.f;
#pragma unroll 8
    for (int d = 0; d < HEAD_DIM; d++) dot += qv[d] * kp[d];
    dot *= scale;
    sc[k] = dot;
    lmax = fmaxf(lmax, dot);
  }
  // block max
  for (int off = 32; off > 0; off >>= 1)
    lmax = fmaxf(lmax, __shfl_down(lmax, off, 64));
  if ((tid & 63) == 0) red[tid >> 6] = lmax;
  __syncthreads();
  float gmax = fmaxf(fmaxf(red[0], red[1]), fmaxf(red[2], red[3]));
  __syncthreads();  // red[] reused below

  // Pass 2: exponentiate + local sum
  float lsum = 0.f;
  for (int k = tid; k < L; k += 256) {
    float e = __expf(sc[k] - gmax);
    sc[k] = e;
    lsum += e;
  }
  for (int off = 32; off > 0; off >>= 1) lsum += __shfl_down(lsum, off, 64);
  if ((tid & 63) == 0) red[tid >> 6] = lsum;
  __syncthreads();  // also publishes all sc[] writes
  float inv = 1.0f / (red[0] + red[1] + red[2] + red[3]);

  // PV: 128 dims, two k-strides (even/odd) across the 256 threads
  const int d = tid & 127;
  const int half = tid >> 7;
  float acc = 0.f;
  for (int k = half; k < L; k += 2)
    acc += sc[k] * Vc[((size_t)k * N_KV + kvh) * HEAD_DIM + d];
  if (half == 1) out2[d] = acc;
  __syncthreads();
  if (half == 0)
    O[((size_t)q * N_HEADS + h) * HEAD_DIM + d] = (acc + out2[d]) * inv;
}

// ---------------------------------------------------------------------------
extern "C" void kernel_launch(void* const* d_in, const int* in_sizes, int n_in,
                              void* d_out, int out_size, void* d_ws, size_t ws_size,
                              hipStream_t stream) {
  const float* X  = (const float*)d_in[0];  // [1, 2048, 4096]
  const float* Wq = (const float*)d_in[1];  // [4096, 4096]
  const float* Wk = (const float*)d_in[2];  // [1024, 4096]
  const float* Wv = (const float*)d_in[3];  // [1024, 4096]
  const float* Wo = (const float*)d_in[4];  // [4096, 4096]
  float* out = (float*)d_out;               // [1, 2048, 4096]

  // Workspace layout (floats): Q | K | V | O  = 2048*(4096+1024+1024+4096) = 84 MB
  float* Q = (float*)d_ws;
  float* K = Q + (size_t)S_LEN * N_HEADS * HEAD_DIM;
  float* V = K + (size_t)S_LEN * N_KV * HEAD_DIM;
  float* O = V + (size_t)S_LEN * N_KV * HEAD_DIM;

  dim3 blk(16, 16);

  // QKV projections
  gemm_f32_bt<<<dim3(4096 / TS, S_LEN / TS), blk, 0, stream>>>(X, Wq, Q, S_LEN, 4096, HIDDEN);
  gemm_f32_bt<<<dim3(1024 / TS, S_LEN / TS), blk, 0, stream>>>(X, Wk, K, S_LEN, 1024, HIDDEN);
  gemm_f32_bt<<<dim3(1024 / TS, S_LEN / TS), blk, 0, stream>>>(X, Wv, V, S_LEN, 1024, HIDDEN);

  // RoPE on Q and K
  int rope_threads = S_LEN * (N_HEADS + N_KV) * 64;
  rope_kernel<<<rope_threads / 256, 256, 0, stream>>>(Q, K);

  // Causal GQA attention
  attn_kernel<<<dim3(S_LEN, N_HEADS), 256, 0, stream>>>(Q, K, V, O);

  // Output projection
  gemm_f32_bt<<<dim3(4096 / TS, S_LEN / TS), blk, 0, stream>>>(O, Wo, out, S_LEN, 4096, HIDDEN);
}

// Round 2
// 4898.912 us; speedup vs baseline: 1.9100x; 1.9100x over previous
//
#include <hip/hip_runtime.h>
#include <hip/hip_bf16.h>
#include <math.h>

// Problem constants
#define S_LEN 2048
#define HIDDEN 4096
#define N_HEADS 32
#define N_KV 8
#define HEAD_DIM 128

// ---------------------------------------------------------------------------
// Generic fp32 GEMM:  C[M,N] = A[M,K] @ B[N,K]^T   (both row-major, K contig)
// 64x64 tile, BK=16, 16x16 threads, 4x4 per thread.
// ---------------------------------------------------------------------------
#define TS 64
#define BK 16

__global__ __launch_bounds__(256) void gemm_f32_bt(
    const float* __restrict__ A, const float* __restrict__ B,
    float* __restrict__ C, int M, int N, int K) {
  __shared__ float As[TS][BK + 1];
  __shared__ float Bs[TS][BK + 1];

  const int tx = threadIdx.x;
  const int ty = threadIdx.y;
  const int tid = ty * 16 + tx;
  const int blockRow = blockIdx.y * TS;
  const int blockCol = blockIdx.x * TS;

  float acc[4][4] = {};

  for (int k0 = 0; k0 < K; k0 += BK) {
#pragma unroll
    for (int i = 0; i < 4; i++) {
      int idx = tid + i * 256;
      int m = idx >> 4;
      int kk = idx & 15;
      As[m][kk] = A[(size_t)(blockRow + m) * K + k0 + kk];
      Bs[m][kk] = B[(size_t)(blockCol + m) * K + k0 + kk];
    }
    __syncthreads();

#pragma unroll
    for (int kk = 0; kk < BK; kk++) {
      float a[4], b[4];
#pragma unroll
      for (int i = 0; i < 4; i++) a[i] = As[ty * 4 + i][kk];
#pragma unroll
      for (int j = 0; j < 4; j++) b[j] = Bs[tx * 4 + j][kk];
#pragma unroll
      for (int i = 0; i < 4; i++)
#pragma unroll
        for (int j = 0; j < 4; j++) acc[i][j] += a[i] * b[j];
    }
    __syncthreads();
  }

#pragma unroll
  for (int i = 0; i < 4; i++)
#pragma unroll
    for (int j = 0; j < 4; j++)
      C[(size_t)(blockRow + ty * 4 + i) * N + blockCol + tx * 4 + j] = acc[i][j];
}

// ---------------------------------------------------------------------------
// RoPE applied in-place to Q [S, 32, 128] and K [S, 8, 128].
// ---------------------------------------------------------------------------
__global__ void rope_kernel(float* __restrict__ Q, float* __restrict__ K) {
  int idx = blockIdx.x * blockDim.x + threadIdx.x;
  int d = idx & 63;
  int sh = idx >> 6;
  int h = sh % (N_HEADS + N_KV);
  int s = sh / (N_HEADS + N_KV);
  if (s >= S_LEN) return;

  float freq = expf(-(float)d * (9.210340371976184f / 64.0f));
  float ang = (float)s * freq;
  float sn, cs;
  sincosf(ang, &sn, &cs);

  float* ptr;
  if (h < N_HEADS)
    ptr = Q + ((size_t)s * N_HEADS + h) * HEAD_DIM;
  else
    ptr = K + ((size_t)s * N_KV + (h - N_HEADS)) * HEAD_DIM;

  float x1 = ptr[d];
  float x2 = ptr[d + 64];
  ptr[d] = x1 * cs - x2 * sn;
  ptr[d + 64] = x2 * cs + x1 * sn;
}

// ---------------------------------------------------------------------------
// Flash-style causal GQA attention, fp32.
// Block = 256 threads per (64-query tile, head). K-tiles of 32.
// Q tile (scaled) persistent in LDS; V prefetched to regs during QK^T and
// written into the K LDS buffer before PV (keeps LDS at 59 KB, 2 blocks/CU).
// Thread (rowg=tid>>4, colg=tid&15): S micro-tile = rows rowg*4..+3, cols
// {colg, colg+16}; PV micro-tile = rows rowg*4..+3, dims {colg*4..+3, 64+colg*4..+3}.
// ---------------------------------------------------------------------------
#define BQ 64
#define BKT 32
#define KSTR 132  // padded row stride (floats): 2-way bank aliasing only (free)
#define PSTR 33

__global__ __launch_bounds__(256) void flash_attn_f32(
    const float* __restrict__ Qg, const float* __restrict__ Kg,
    const float* __restrict__ Vg, float* __restrict__ Og) {
  const int h = blockIdx.y;
  const int qb = blockIdx.x * BQ;
  const int kvh = h >> 2;
  const int tid = threadIdx.x;
  const int rowg = tid >> 4;  // 0..15
  const int colg = tid & 15;  // 0..15

  __shared__ __align__(16) float Qs[BQ * KSTR];    // 33792 B
  __shared__ __align__(16) float KVs[BKT * KSTR];  // 16896 B
  __shared__ __align__(16) float Ps[BQ * PSTR];    //  8448 B  -> 59136 B total

  const float scale = 0.08838834764831845f;  // 1/sqrt(128)

  // Load Q tile, folding in the softmax scale. 2048 float4, 8 per thread.
#pragma unroll
  for (int i = 0; i < 8; i++) {
    int idx = tid + i * 256;
    int r = idx >> 5;
    int c4 = idx & 31;
    float4 v = *(const float4*)&Qg[((size_t)(qb + r) * N_HEADS + h) * HEAD_DIM + c4 * 4];
    v.x *= scale; v.y *= scale; v.z *= scale; v.w *= scale;
    *(float4*)&Qs[r * KSTR + c4 * 4] = v;
  }

  float m_i[4], l_i[4], acc[4][8];
#pragma unroll
  for (int i = 0; i < 4; i++) {
    m_i[i] = -1e30f;
    l_i[i] = 0.f;
#pragma unroll
    for (int j = 0; j < 8; j++) acc[i][j] = 0.f;
  }

  const int c0 = colg, c1 = colg + 16;
  const int nkt = qb / BKT + 2;  // causal: tiles through kb = qb+32

  for (int kt = 0; kt < nkt; kt++) {
    const int kb = kt * BKT;
    __syncthreads();  // prior iter done with KVs/Ps; Qs visible on iter 0

    // Stage K tile into LDS (1024 float4, 4/thread)
#pragma unroll
    for (int i = 0; i < 4; i++) {
      int idx = tid + i * 256;
      int r = idx >> 5, c4 = idx & 31;
      *(float4*)&KVs[r * KSTR + c4 * 4] =
          *(const float4*)&Kg[((size_t)(kb + r) * N_KV + kvh) * HEAD_DIM + c4 * 4];
    }
    // Prefetch V tile into registers (latency hidden behind QK^T)
    float4 vr[4];
#pragma unroll
    for (int i = 0; i < 4; i++) {
      int idx = tid + i * 256;
      int r = idx >> 5, c4 = idx & 31;
      vr[i] = *(const float4*)&Vg[((size_t)(kb + r) * N_KV + kvh) * HEAD_DIM + c4 * 4];
    }
    __syncthreads();  // K visible

    // S = (Q*scale) K^T : 4 rows x 2 cols per thread
    float s[4][2] = {{0.f, 0.f}, {0.f, 0.f}, {0.f, 0.f}, {0.f, 0.f}};
#pragma unroll 4
    for (int d4 = 0; d4 < 32; d4++) {
      float4 k0 = *(const float4*)&KVs[c0 * KSTR + d4 * 4];
      float4 k1 = *(const float4*)&KVs[c1 * KSTR + d4 * 4];
#pragma unroll
      for (int i = 0; i < 4; i++) {
        float4 qv = *(const float4*)&Qs[(rowg * 4 + i) * KSTR + d4 * 4];
        s[i][0] += qv.x * k0.x + qv.y * k0.y + qv.z * k0.z + qv.w * k0.w;
        s[i][1] += qv.x * k1.x + qv.y * k1.y + qv.z * k1.z + qv.w * k1.w;
      }
    }

    // Causal mask (only the last two tiles can clip)
    if (kb >= qb) {
      int rbase = qb + rowg * 4;
#pragma unroll
      for (int i = 0; i < 4; i++) {
        if (kb + c0 > rbase + i) s[i][0] = -1e30f;
        if (kb + c1 > rbase + i) s[i][1] = -1e30f;
      }
    }

    // Online softmax: row stats across the 16 colg lanes (XOR shuffles)
    float p[4][2], alpha[4];
#pragma unroll
    for (int i = 0; i < 4; i++) {
      float lm = fmaxf(s[i][0], s[i][1]);
      for (int mo = 1; mo < 16; mo <<= 1) lm = fmaxf(lm, __shfl_xor(lm, mo, 64));
      float mn = fmaxf(m_i[i], lm);
      alpha[i] = __expf(m_i[i] - mn);
      m_i[i] = mn;
      p[i][0] = __expf(s[i][0] - mn);
      p[i][1] = __expf(s[i][1] - mn);
      float ls = p[i][0] + p[i][1];
      for (int mo = 1; mo < 16; mo <<= 1) ls += __shfl_xor(ls, mo, 64);
      l_i[i] = l_i[i] * alpha[i] + ls;
    }

    __syncthreads();  // all waves done reading K from KVs

    // Write V (regs -> KVs) and P (-> Ps)
#pragma unroll
    for (int i = 0; i < 4; i++) {
      int idx = tid + i * 256;
      int r = idx >> 5, c4 = idx & 31;
      *(float4*)&KVs[r * KSTR + c4 * 4] = vr[i];
    }
#pragma unroll
    for (int i = 0; i < 4; i++) {
      Ps[(rowg * 4 + i) * PSTR + c0] = p[i][0];
      Ps[(rowg * 4 + i) * PSTR + c1] = p[i][1];
    }
    // Rescale accumulators
#pragma unroll
    for (int i = 0; i < 4; i++)
#pragma unroll
      for (int j = 0; j < 8; j++) acc[i][j] *= alpha[i];

    __syncthreads();  // V, P visible

    // O += P V : 4 rows x 8 dims per thread
#pragma unroll 4
    for (int k = 0; k < BKT; k++) {
      float4 v0 = *(const float4*)&KVs[k * KSTR + colg * 4];
      float4 v1 = *(const float4*)&KVs[k * KSTR + 64 + colg * 4];
#pragma unroll
      for (int i = 0; i < 4; i++) {
        float pv = Ps[(rowg * 4 + i) * PSTR + k];
        acc[i][0] += pv * v0.x; acc[i][1] += pv * v0.y;
        acc[i][2] += pv * v0.z; acc[i][3] += pv * v0.w;
        acc[i][4] += pv * v1.x; acc[i][5] += pv * v1.y;
        acc[i][6] += pv * v1.z; acc[i][7] += pv * v1.w;
      }
    }
  }

  // Epilogue: normalize and store
#pragma unroll
  for (int i = 0; i < 4; i++) {
    float inv = 1.0f / l_i[i];
    int row = qb + rowg * 4 + i;
    float4 o0 = make_float4(acc[i][0] * inv, acc[i][1] * inv, acc[i][2] * inv, acc[i][3] * inv);
    float4 o1 = make_float4(acc[i][4] * inv, acc[i][5] * inv, acc[i][6] * inv, acc[i][7] * inv);
    *(float4*)&Og[((size_t)row * N_HEADS + h) * HEAD_DIM + colg * 4] = o0;
    *(float4*)&Og[((size_t)row * N_HEADS + h) * HEAD_DIM + 64 + colg * 4] = o1;
  }
}

// ---------------------------------------------------------------------------
extern "C" void kernel_launch(void* const* d_in, const int* in_sizes, int n_in,
                              void* d_out, int out_size, void* d_ws, size_t ws_size,
                              hipStream_t stream) {
  const float* X  = (const float*)d_in[0];
  const float* Wq = (const float*)d_in[1];
  const float* Wk = (const float*)d_in[2];
  const float* Wv = (const float*)d_in[3];
  const float* Wo = (const float*)d_in[4];
  float* out = (float*)d_out;

  float* Q = (float*)d_ws;
  float* K = Q + (size_t)S_LEN * N_HEADS * HEAD_DIM;
  float* V = K + (size_t)S_LEN * N_KV * HEAD_DIM;
  float* O = V + (size_t)S_LEN * N_KV * HEAD_DIM;

  dim3 blk(16, 16);

  gemm_f32_bt<<<dim3(4096 / TS, S_LEN / TS), blk, 0, stream>>>(X, Wq, Q, S_LEN, 4096, HIDDEN);
  gemm_f32_bt<<<dim3(1024 / TS, S_LEN / TS), blk, 0, stream>>>(X, Wk, K, S_LEN, 1024, HIDDEN);
  gemm_f32_bt<<<dim3(1024 / TS, S_LEN / TS), blk, 0, stream>>>(X, Wv, V, S_LEN, 1024, HIDDEN);

  int rope_threads = S_LEN * (N_HEADS + N_KV) * 64;
  rope_kernel<<<rope_threads / 256, 256, 0, stream>>>(Q, K);

  flash_attn_f32<<<dim3(S_LEN / BQ, N_HEADS), 256, 0, stream>>>(Q, K, V, O);

  gemm_f32_bt<<<dim3(4096 / TS, S_LEN / TS), blk, 0, stream>>>(O, Wo, out, S_LEN, 4096, HIDDEN);
}

// Round 3
// 1717.672 us; speedup vs baseline: 5.4473x; 2.8521x over previous
//
#include <hip/hip_runtime.h>
#include <hip/hip_bf16.h>
#include <math.h>

// Problem constants
#define S_LEN 2048
#define HIDDEN 4096
#define N_HEADS 32
#define N_KV 8
#define HEAD_DIM 128

typedef __attribute__((ext_vector_type(8))) short short8;   // 8 bf16 = 4 VGPRs
typedef __attribute__((ext_vector_type(4))) float f32x4;    // MFMA C/D frag

typedef __attribute__((address_space(3))) unsigned int as3_u32;
typedef const __attribute__((address_space(1))) unsigned int as1_u32;

__device__ __forceinline__ void gload16(const void* g, void* lds) {
  // async global->LDS, 16 B per lane; LDS dest = wave-uniform base + lane*16
  __builtin_amdgcn_global_load_lds((as1_u32*)g, (as3_u32*)lds, 16, 0, 0);
}

__device__ __forceinline__ unsigned short f2bf(float f) {
  unsigned int u = __float_as_uint(f);
  return (unsigned short)((u + 0x7fff + ((u >> 16) & 1)) >> 16);  // RNE
}

// ---------------------------------------------------------------------------
// fp32 -> bf16 conversion, 4 elems/thread
// ---------------------------------------------------------------------------
__global__ void conv_bf16(const float* __restrict__ in, unsigned short* __restrict__ out, int n) {
  int i = (blockIdx.x * blockDim.x + threadIdx.x) * 4;
  if (i >= n) return;
  float4 v = *(const float4*)&in[i];
  ushort4 o;
  o.x = f2bf(v.x); o.y = f2bf(v.y); o.z = f2bf(v.z); o.w = f2bf(v.w);
  *(ushort4*)&out[i] = o;
}

// ---------------------------------------------------------------------------
// m97-style bf16 MFMA GEMM core: one 128x128 C-tile per 256-thread block.
// A: [.,K] bf16 row-major (pre-offset to tile row 0). B: weight rows = C cols,
// [.,K] bf16 (pre-offset to tile col 0's weight row). C: fp32, pre-offset to
// (tile row 0, tile col 0), leading dim ldc. K multiple of 32.
// Per wave: 64x64 output = 4x4 mfma_f32_16x16x32_bf16 tiles.
// ---------------------------------------------------------------------------
__device__ __forceinline__ void gemm_core_128(
    const unsigned short* __restrict__ A, const unsigned short* __restrict__ B,
    float* __restrict__ C, int K, int ldc) {
  __shared__ unsigned short As[128 * 32];  // 8 KB
  __shared__ unsigned short Bs[128 * 32];  // 8 KB

  const int tid = threadIdx.x;
  const int w = tid >> 6;        // wave 0..3
  const int lane = tid & 63;
  const int wr = (w >> 1) * 64;  // wave's C rows
  const int wc = (w & 1) * 64;   // wave's C cols
  const int lrow = lane & 15;    // fragment row/col within 16
  const int lk8 = lane >> 4;     // k-chunk 0..3 (8 bf16 each)

  f32x4 acc[4][4];
#pragma unroll
  for (int i = 0; i < 4; i++)
#pragma unroll
    for (int j = 0; j < 4; j++) acc[i][j] = (f32x4){0.f, 0.f, 0.f, 0.f};

  // staging coords: per wave-instr, 16 rows x 32 k; lane i -> row i/4, chunk i%4
  const int sr = (lane >> 2);       // 0..15
  const int sc = (lane & 3) * 8;    // 0,8,16,24

  for (int k0 = 0; k0 < K; k0 += 32) {
    __syncthreads();  // previous iter's reads done
#pragma unroll
    for (int s = 0; s < 2; s++) {
      int r = w * 32 + s * 16 + sr;
      gload16(&A[(size_t)r * K + k0 + sc], &As[(w * 32 + s * 16) * 32]);
      gload16(&B[(size_t)r * K + k0 + sc], &Bs[(w * 32 + s * 16) * 32]);
    }
    __syncthreads();  // staged data visible (barrier drains vmcnt)

    short8 a[4], b[4];
#pragma unroll
    for (int i = 0; i < 4; i++)
      a[i] = *(const short8*)&As[(wr + i * 16 + lrow) * 32 + lk8 * 8];
#pragma unroll
    for (int j = 0; j < 4; j++)
      b[j] = *(const short8*)&Bs[(wc + j * 16 + lrow) * 32 + lk8 * 8];
#pragma unroll
    for (int i = 0; i < 4; i++)
#pragma unroll
      for (int j = 0; j < 4; j++)
        acc[i][j] = __builtin_amdgcn_mfma_f32_16x16x32_bf16(a[i], b[j], acc[i][j], 0, 0, 0);
  }

  // Epilogue: C/D layout col=lane&15, row=(lane>>4)*4+reg  [verified m89]
#pragma unroll
  for (int i = 0; i < 4; i++)
#pragma unroll
    for (int j = 0; j < 4; j++) {
      int col = wc + j * 16 + lrow;
#pragma unroll
      for (int r = 0; r < 4; r++) {
        int row = wr + i * 16 + lk8 * 4 + r;
        C[(size_t)row * ldc + col] = acc[i][j][r];
      }
    }
}

// Fused QKV projection: N = 4096 (Q) + 1024 (K) + 1024 (V), K = 4096.
__global__ __launch_bounds__(256) void gemm_qkv(
    const unsigned short* __restrict__ Xb,
    const unsigned short* __restrict__ Wqb, const unsigned short* __restrict__ Wkb,
    const unsigned short* __restrict__ Wvb,
    float* __restrict__ Q, float* __restrict__ Ko, float* __restrict__ Vo) {
  const int colBase = blockIdx.x * 128;  // 0..6143
  const int rowBase = blockIdx.y * 128;
  const unsigned short* B;
  float* C;
  int ldc, ccol;
  if (colBase < 4096)      { B = Wqb + (size_t)colBase * HIDDEN;          C = Q;  ldc = 4096; ccol = colBase; }
  else if (colBase < 5120) { B = Wkb + (size_t)(colBase - 4096) * HIDDEN; C = Ko; ldc = 1024; ccol = colBase - 4096; }
  else                     { B = Wvb + (size_t)(colBase - 5120) * HIDDEN; C = Vo; ldc = 1024; ccol = colBase - 5120; }
  gemm_core_128(Xb + (size_t)rowBase * HIDDEN, B,
                C + (size_t)rowBase * ldc + ccol, HIDDEN, ldc);
}

// Output projection: [2048,4096] @ Wo^T -> [2048,4096]
__global__ __launch_bounds__(256) void gemm_out(
    const unsigned short* __restrict__ Ob, const unsigned short* __restrict__ Wob,
    float* __restrict__ C) {
  const int colBase = blockIdx.x * 128;
  const int rowBase = blockIdx.y * 128;
  gemm_core_128(Ob + (size_t)rowBase * HIDDEN, Wob + (size_t)colBase * HIDDEN,
                C + (size_t)rowBase * HIDDEN + colBase, HIDDEN, HIDDEN);
}

// ---------------------------------------------------------------------------
// RoPE in-place on fp32 Q [S, 32, 128] and K [S, 8, 128].
// ---------------------------------------------------------------------------
__global__ void rope_kernel(float* __restrict__ Q, float* __restrict__ K) {
  int idx = blockIdx.x * blockDim.x + threadIdx.x;
  int d = idx & 63;
  int sh = idx >> 6;
  int h = sh % (N_HEADS + N_KV);
  int s = sh / (N_HEADS + N_KV);
  if (s >= S_LEN) return;

  float freq = expf(-(float)d * (9.210340371976184f / 64.0f));
  float ang = (float)s * freq;
  float sn, cs;
  sincosf(ang, &sn, &cs);

  float* ptr;
  if (h < N_HEADS)
    ptr = Q + ((size_t)s * N_HEADS + h) * HEAD_DIM;
  else
    ptr = K + ((size_t)s * N_KV + (h - N_HEADS)) * HEAD_DIM;

  float x1 = ptr[d];
  float x2 = ptr[d + 64];
  ptr[d] = x1 * cs - x2 * sn;
  ptr[d + 64] = x2 * cs + x1 * sn;
}

// ---------------------------------------------------------------------------
// Flash-style causal GQA attention, fp32 compute, bf16 output.
// ---------------------------------------------------------------------------
#define BQ 64
#define BKT 32
#define KSTR 132
#define PSTR 33

__global__ __launch_bounds__(256) void flash_attn_f32(
    const float* __restrict__ Qg, const float* __restrict__ Kg,
    const float* __restrict__ Vg, unsigned short* __restrict__ Ob) {
  const int h = blockIdx.y;
  const int qb = blockIdx.x * BQ;
  const int kvh = h >> 2;
  const int tid = threadIdx.x;
  const int rowg = tid >> 4;
  const int colg = tid & 15;

  __shared__ __align__(16) float Qs[BQ * KSTR];
  __shared__ __align__(16) float KVs[BKT * KSTR];
  __shared__ __align__(16) float Ps[BQ * PSTR];

  const float scale = 0.08838834764831845f;

#pragma unroll
  for (int i = 0; i < 8; i++) {
    int idx = tid + i * 256;
    int r = idx >> 5;
    int c4 = idx & 31;
    float4 v = *(const float4*)&Qg[((size_t)(qb + r) * N_HEADS + h) * HEAD_DIM + c4 * 4];
    v.x *= scale; v.y *= scale; v.z *= scale; v.w *= scale;
    *(float4*)&Qs[r * KSTR + c4 * 4] = v;
  }

  float m_i[4], l_i[4], acc[4][8];
#pragma unroll
  for (int i = 0; i < 4; i++) {
    m_i[i] = -1e30f;
    l_i[i] = 0.f;
#pragma unroll
    for (int j = 0; j < 8; j++) acc[i][j] = 0.f;
  }

  const int c0 = colg, c1 = colg + 16;
  const int nkt = qb / BKT + 2;

  for (int kt = 0; kt < nkt; kt++) {
    const int kb = kt * BKT;
    __syncthreads();

#pragma unroll
    for (int i = 0; i < 4; i++) {
      int idx = tid + i * 256;
      int r = idx >> 5, c4 = idx & 31;
      *(float4*)&KVs[r * KSTR + c4 * 4] =
          *(const float4*)&Kg[((size_t)(kb + r) * N_KV + kvh) * HEAD_DIM + c4 * 4];
    }
    float4 vr[4];
#pragma unroll
    for (int i = 0; i < 4; i++) {
      int idx = tid + i * 256;
      int r = idx >> 5, c4 = idx & 31;
      vr[i] = *(const float4*)&Vg[((size_t)(kb + r) * N_KV + kvh) * HEAD_DIM + c4 * 4];
    }
    __syncthreads();

    float s[4][2] = {{0.f, 0.f}, {0.f, 0.f}, {0.f, 0.f}, {0.f, 0.f}};
#pragma unroll 4
    for (int d4 = 0; d4 < 32; d4++) {
      float4 k0 = *(const float4*)&KVs[c0 * KSTR + d4 * 4];
      float4 k1 = *(const float4*)&KVs[c1 * KSTR + d4 * 4];
#pragma unroll
      for (int i = 0; i < 4; i++) {
        float4 qv = *(const float4*)&Qs[(rowg * 4 + i) * KSTR + d4 * 4];
        s[i][0] += qv.x * k0.x + qv.y * k0.y + qv.z * k0.z + qv.w * k0.w;
        s[i][1] += qv.x * k1.x + qv.y * k1.y + qv.z * k1.z + qv.w * k1.w;
      }
    }

    if (kb >= qb) {
      int rbase = qb + rowg * 4;
#pragma unroll
      for (int i = 0; i < 4; i++) {
        if (kb + c0 > rbase + i) s[i][0] = -1e30f;
        if (kb + c1 > rbase + i) s[i][1] = -1e30f;
      }
    }

    float p[4][2], alpha[4];
#pragma unroll
    for (int i = 0; i < 4; i++) {
      float lm = fmaxf(s[i][0], s[i][1]);
      for (int mo = 1; mo < 16; mo <<= 1) lm = fmaxf(lm, __shfl_xor(lm, mo, 64));
      float mn = fmaxf(m_i[i], lm);
      alpha[i] = __expf(m_i[i] - mn);
      m_i[i] = mn;
      p[i][0] = __expf(s[i][0] - mn);
      p[i][1] = __expf(s[i][1] - mn);
      float ls = p[i][0] + p[i][1];
      for (int mo = 1; mo < 16; mo <<= 1) ls += __shfl_xor(ls, mo, 64);
      l_i[i] = l_i[i] * alpha[i] + ls;
    }

    __syncthreads();

#pragma unroll
    for (int i = 0; i < 4; i++) {
      int idx = tid + i * 256;
      int r = idx >> 5, c4 = idx & 31;
      *(float4*)&KVs[r * KSTR + c4 * 4] = vr[i];
    }
#pragma unroll
    for (int i = 0; i < 4; i++) {
      Ps[(rowg * 4 + i) * PSTR + c0] = p[i][0];
      Ps[(rowg * 4 + i) * PSTR + c1] = p[i][1];
    }
#pragma unroll
    for (int i = 0; i < 4; i++)
#pragma unroll
      for (int j = 0; j < 8; j++) acc[i][j] *= alpha[i];

    __syncthreads();

#pragma unroll 4
    for (int k = 0; k < BKT; k++) {
      float4 v0 = *(const float4*)&KVs[k * KSTR + colg * 4];
      float4 v1 = *(const float4*)&KVs[k * KSTR + 64 + colg * 4];
#pragma unroll
      for (int i = 0; i < 4; i++) {
        float pv = Ps[(rowg * 4 + i) * PSTR + k];
        acc[i][0] += pv * v0.x; acc[i][1] += pv * v0.y;
        acc[i][2] += pv * v0.z; acc[i][3] += pv * v0.w;
        acc[i][4] += pv * v1.x; acc[i][5] += pv * v1.y;
        acc[i][6] += pv * v1.z; acc[i][7] += pv * v1.w;
      }
    }
  }

  // Epilogue: normalize, convert to bf16, store [S, 4096]
#pragma unroll
  for (int i = 0; i < 4; i++) {
    float inv = 1.0f / l_i[i];
    int row = qb + rowg * 4 + i;
    ushort4 o0, o1;
    o0.x = f2bf(acc[i][0] * inv); o0.y = f2bf(acc[i][1] * inv);
    o0.z = f2bf(acc[i][2] * inv); o0.w = f2bf(acc[i][3] * inv);
    o1.x = f2bf(acc[i][4] * inv); o1.y = f2bf(acc[i][5] * inv);
    o1.z = f2bf(acc[i][6] * inv); o1.w = f2bf(acc[i][7] * inv);
    size_t base = (size_t)row * HIDDEN + h * HEAD_DIM;
    *(ushort4*)&Ob[base + colg * 4] = o0;
    *(ushort4*)&Ob[base + 64 + colg * 4] = o1;
  }
}

// ---------------------------------------------------------------------------
extern "C" void kernel_launch(void* const* d_in, const int* in_sizes, int n_in,
                              void* d_out, int out_size, void* d_ws, size_t ws_size,
                              hipStream_t stream) {
  const float* X  = (const float*)d_in[0];
  const float* Wq = (const float*)d_in[1];
  const float* Wk = (const float*)d_in[2];
  const float* Wv = (const float*)d_in[3];
  const float* Wo = (const float*)d_in[4];
  float* out = (float*)d_out;

  // Workspace layout (bytes). Aliases: Ob reuses Xb (Xb dead after gemm_qkv),
  // Wob reuses Wqb (dead after gemm_qkv).
  char* p = (char*)d_ws;
  float* Qf = (float*)p;                 p += (size_t)S_LEN * 4096 * 4;  // 33.5 MB
  float* Kf = (float*)p;                 p += (size_t)S_LEN * 1024 * 4;  //  8.4 MB
  float* Vf = (float*)p;                 p += (size_t)S_LEN * 1024 * 4;  //  8.4 MB
  unsigned short* Xb = (unsigned short*)p;  p += (size_t)S_LEN * 4096 * 2;   // 16.8 MB
  unsigned short* Wqb = (unsigned short*)p; p += (size_t)4096 * 4096 * 2;    // 33.6 MB
  unsigned short* Wkb = (unsigned short*)p; p += (size_t)1024 * 4096 * 2;    //  8.4 MB
  unsigned short* Wvb = (unsigned short*)p; p += (size_t)1024 * 4096 * 2;    //  8.4 MB
  unsigned short* Ob = Xb;
  unsigned short* Wob = Wqb;

  // 1. fp32 -> bf16 conversions
  conv_bf16<<<(S_LEN * 4096 / 4 + 255) / 256, 256, 0, stream>>>(X, Xb, S_LEN * 4096);
  conv_bf16<<<(4096 * 4096 / 4 + 255) / 256, 256, 0, stream>>>(Wq, Wqb, 4096 * 4096);
  conv_bf16<<<(1024 * 4096 / 4 + 255) / 256, 256, 0, stream>>>(Wk, Wkb, 1024 * 4096);
  conv_bf16<<<(1024 * 4096 / 4 + 255) / 256, 256, 0, stream>>>(Wv, Wvb, 1024 * 4096);

  // 2. Fused QKV projection (MFMA bf16)
  gemm_qkv<<<dim3(6144 / 128, S_LEN / 128), 256, 0, stream>>>(Xb, Wqb, Wkb, Wvb, Qf, Kf, Vf);

  // 3. RoPE on fp32 Q, K
  int rope_threads = S_LEN * (N_HEADS + N_KV) * 64;
  rope_kernel<<<rope_threads / 256, 256, 0, stream>>>(Qf, Kf);

  // 4. Convert Wo (into Wqb's space — safe after gemm_qkv)
  conv_bf16<<<(4096 * 4096 / 4 + 255) / 256, 256, 0, stream>>>(Wo, Wob, 4096 * 4096);

  // 5. Attention (writes bf16 into Xb's space — safe after gemm_qkv)
  flash_attn_f32<<<dim3(S_LEN / BQ, N_HEADS), 256, 0, stream>>>(Qf, Kf, Vf, Ob);

  // 6. Output projection (MFMA bf16)
  gemm_out<<<dim3(4096 / 128, S_LEN / 128), 256, 0, stream>>>(Ob, Wob, out);
}

// Round 4
// 710.508 us; speedup vs baseline: 13.1691x; 2.4175x over previous
//
#include <hip/hip_runtime.h>
#include <hip/hip_bf16.h>
#include <math.h>

// Problem constants
#define S_LEN 2048
#define HIDDEN 4096
#define N_HEADS 32
#define N_KV 8
#define HEAD_DIM 128

typedef __attribute__((ext_vector_type(8))) short short8;   // 8 bf16 = 4 VGPRs
typedef __attribute__((ext_vector_type(4))) float f32x4;    // MFMA C/D frag

typedef __attribute__((address_space(3))) unsigned int as3_u32;
typedef const __attribute__((address_space(1))) unsigned int as1_u32;

__device__ __forceinline__ void gload16(const void* g, void* lds) {
  __builtin_amdgcn_global_load_lds((as1_u32*)g, (as3_u32*)lds, 16, 0, 0);
}

__device__ __forceinline__ unsigned short f2bf(float f) {
  unsigned int u = __float_as_uint(f);
  return (unsigned short)((u + 0x7fff + ((u >> 16) & 1)) >> 16);  // RNE
}
__device__ __forceinline__ float bf2f(unsigned short u) {
  return __uint_as_float(((unsigned int)u) << 16);
}

// ---------------------------------------------------------------------------
// fp32 -> bf16 conversion, 4 elems/thread
// ---------------------------------------------------------------------------
__global__ void conv_bf16(const float* __restrict__ in, unsigned short* __restrict__ out, int n) {
  int i = (blockIdx.x * blockDim.x + threadIdx.x) * 4;
  if (i >= n) return;
  float4 v = *(const float4*)&in[i];
  ushort4 o;
  o.x = f2bf(v.x); o.y = f2bf(v.y); o.z = f2bf(v.z); o.w = f2bf(v.w);
  *(ushort4*)&out[i] = o;
}

// ---------------------------------------------------------------------------
// m97-style bf16 MFMA GEMM core: one 128x128 C-tile per 256-thread block.
// Output type templated: float (fp32 store) or ushort (bf16 store).
// ---------------------------------------------------------------------------
__device__ __forceinline__ void storeC(float* C, float v) { *C = v; }
__device__ __forceinline__ void storeC(unsigned short* C, float v) { *C = f2bf(v); }

template <typename OutT>
__device__ __forceinline__ void gemm_core_128(
    const unsigned short* __restrict__ A, const unsigned short* __restrict__ B,
    OutT* __restrict__ C, int K, int ldc) {
  __shared__ unsigned short As[128 * 32];
  __shared__ unsigned short Bs[128 * 32];

  const int tid = threadIdx.x;
  const int w = tid >> 6;
  const int lane = tid & 63;
  const int wr = (w >> 1) * 64;
  const int wc = (w & 1) * 64;
  const int lrow = lane & 15;
  const int lk8 = lane >> 4;

  f32x4 acc[4][4];
#pragma unroll
  for (int i = 0; i < 4; i++)
#pragma unroll
    for (int j = 0; j < 4; j++) acc[i][j] = (f32x4){0.f, 0.f, 0.f, 0.f};

  const int sr = (lane >> 2);
  const int sc = (lane & 3) * 8;

  for (int k0 = 0; k0 < K; k0 += 32) {
    __syncthreads();
#pragma unroll
    for (int s = 0; s < 2; s++) {
      int r = w * 32 + s * 16 + sr;
      gload16(&A[(size_t)r * K + k0 + sc], &As[(w * 32 + s * 16) * 32]);
      gload16(&B[(size_t)r * K + k0 + sc], &Bs[(w * 32 + s * 16) * 32]);
    }
    __syncthreads();

    short8 a[4], b[4];
#pragma unroll
    for (int i = 0; i < 4; i++)
      a[i] = *(const short8*)&As[(wr + i * 16 + lrow) * 32 + lk8 * 8];
#pragma unroll
    for (int j = 0; j < 4; j++)
      b[j] = *(const short8*)&Bs[(wc + j * 16 + lrow) * 32 + lk8 * 8];
#pragma unroll
    for (int i = 0; i < 4; i++)
#pragma unroll
      for (int j = 0; j < 4; j++)
        acc[i][j] = __builtin_amdgcn_mfma_f32_16x16x32_bf16(a[i], b[j], acc[i][j], 0, 0, 0);
  }

#pragma unroll
  for (int i = 0; i < 4; i++)
#pragma unroll
    for (int j = 0; j < 4; j++) {
      int col = wc + j * 16 + lrow;
#pragma unroll
      for (int r = 0; r < 4; r++) {
        int row = wr + i * 16 + lk8 * 4 + r;
        storeC(&C[(size_t)row * ldc + col], acc[i][j][r]);
      }
    }
}

// Fused QKV projection -> bf16 outputs Qb [S,4096], Kb [S,1024], Vb [S,1024]
__global__ __launch_bounds__(256) void gemm_qkv(
    const unsigned short* __restrict__ Xb,
    const unsigned short* __restrict__ Wqb, const unsigned short* __restrict__ Wkb,
    const unsigned short* __restrict__ Wvb,
    unsigned short* __restrict__ Qb, unsigned short* __restrict__ Kb,
    unsigned short* __restrict__ Vb) {
  const int colBase = blockIdx.x * 128;
  const int rowBase = blockIdx.y * 128;
  const unsigned short* B;
  unsigned short* C;
  int ldc, ccol;
  if (colBase < 4096)      { B = Wqb + (size_t)colBase * HIDDEN;          C = Qb; ldc = 4096; ccol = colBase; }
  else if (colBase < 5120) { B = Wkb + (size_t)(colBase - 4096) * HIDDEN; C = Kb; ldc = 1024; ccol = colBase - 4096; }
  else                     { B = Wvb + (size_t)(colBase - 5120) * HIDDEN; C = Vb; ldc = 1024; ccol = colBase - 5120; }
  gemm_core_128(Xb + (size_t)rowBase * HIDDEN, B,
                C + (size_t)rowBase * ldc + ccol, HIDDEN, ldc);
}

// Output projection: [2048,4096](bf16) @ Wo^T -> fp32 out
__global__ __launch_bounds__(256) void gemm_out(
    const unsigned short* __restrict__ Ob, const unsigned short* __restrict__ Wob,
    float* __restrict__ C) {
  const int colBase = blockIdx.x * 128;
  const int rowBase = blockIdx.y * 128;
  gemm_core_128(Ob + (size_t)rowBase * HIDDEN, Wob + (size_t)colBase * HIDDEN,
                C + (size_t)rowBase * HIDDEN + colBase, HIDDEN, HIDDEN);
}

// ---------------------------------------------------------------------------
// RoPE in-place on bf16 Q [S,32,128] and K [S,8,128].
// Q additionally scaled by 1/sqrt(128) * log2(e)  (exp2-domain softmax).
// ---------------------------------------------------------------------------
#define QSCALE 0.12753102123752056f  // 0.08838834764831845 * 1.4426950408889634

__global__ void rope_kernel(unsigned short* __restrict__ Q, unsigned short* __restrict__ K) {
  int idx = blockIdx.x * blockDim.x + threadIdx.x;
  int d = idx & 63;
  int sh = idx >> 6;
  int h = sh % (N_HEADS + N_KV);
  int s = sh / (N_HEADS + N_KV);
  if (s >= S_LEN) return;

  float freq = expf(-(float)d * (9.210340371976184f / 64.0f));
  float ang = (float)s * freq;
  float sn, cs;
  sincosf(ang, &sn, &cs);

  unsigned short* ptr;
  float sc_out;
  if (h < N_HEADS) {
    ptr = Q + ((size_t)s * N_HEADS + h) * HEAD_DIM;
    sc_out = QSCALE;
  } else {
    ptr = K + ((size_t)s * N_KV + (h - N_HEADS)) * HEAD_DIM;
    sc_out = 1.0f;
  }

  float x1 = bf2f(ptr[d]);
  float x2 = bf2f(ptr[d + 64]);
  ptr[d] = f2bf((x1 * cs - x2 * sn) * sc_out);
  ptr[d + 64] = f2bf((x2 * cs + x1 * sn) * sc_out);
}

// ---------------------------------------------------------------------------
// V transpose: Vb [S,1024] bf16 -> Vt [1024,S] bf16 (per-dim rows, key contig)
// ---------------------------------------------------------------------------
__global__ __launch_bounds__(256) void transp_v(
    const unsigned short* __restrict__ Vb, unsigned short* __restrict__ Vt) {
  __shared__ unsigned short t[64][72];
  const int s0 = blockIdx.x * 64;
  const int c0 = blockIdx.y * 64;
  const int tid = threadIdx.x;
#pragma unroll
  for (int i = 0; i < 2; i++) {
    int c = tid + i * 256;          // 512 chunks of 8
    int r = c >> 3, ch = c & 7;
    *(short8*)&t[r][ch * 8] = *(const short8*)&Vb[(size_t)(s0 + r) * 1024 + c0 + ch * 8];
  }
  __syncthreads();
#pragma unroll
  for (int i = 0; i < 4; i++) {
    int c = tid + i * 256;          // 1024 chunks of 4
    int orow = c >> 4, oc4 = (c & 15) * 4;
    ushort4 o;
    o.x = t[oc4 + 0][orow]; o.y = t[oc4 + 1][orow];
    o.z = t[oc4 + 2][orow]; o.w = t[oc4 + 3][orow];
    *(ushort4*)&Vt[(size_t)(c0 + orow) * S_LEN + s0 + oc4] = o;
  }
}

// ---------------------------------------------------------------------------
// MFMA flash attention (bf16, exp2-domain online softmax).
// Block: 128 queries x 1 head, 4 waves (32 q-rows each). K-tiles of 64.
// Q frags in registers; K & V^T staged in padded LDS; P via wave-private LDS.
// ---------------------------------------------------------------------------
#define AQ 128
#define AK 64
#define KS_STR 136  // 64x128 tile rows padded: bank offset 4/row
#define VT_STR 72
#define PS_STR 72

__global__ __launch_bounds__(256) void attn_mfma(
    const unsigned short* __restrict__ Qb, const unsigned short* __restrict__ Kb,
    const unsigned short* __restrict__ Vt, unsigned short* __restrict__ Ob) {
  int bidx = blockIdx.x;
  int qi = bidx & 15;
  int h = bidx >> 4;
  if (bidx >= 256) qi = 15 - qi;  // pair big+small q-tiles across the grid
  const int qb = qi * AQ;
  const int kvh = h >> 2;

  const int tid = threadIdx.x;
  const int w = tid >> 6;
  const int lane = tid & 63;
  const int lrow = lane & 15;
  const int lk8 = lane >> 4;

  __shared__ unsigned short Ks[64 * KS_STR];   // 17408 B (also Q staging)
  __shared__ unsigned short Vts[128 * VT_STR]; // 18432 B
  __shared__ unsigned short Ps[128 * PS_STR];  // 18432 B

  // ---- Load Q fragments into registers (two 64-row staging passes) ----
  short8 qf[2][4];
#pragma unroll
  for (int p = 0; p < 2; p++) {
    __syncthreads();
#pragma unroll
    for (int i = 0; i < 4; i++) {
      int c = tid + i * 256;
      int r = c >> 4, ch = c & 15;
      *(short8*)&Ks[r * KS_STR + ch * 8] =
          *(const short8*)&Qb[(size_t)(qb + p * 64 + r) * 4096 + h * 128 + ch * 8];
    }
    __syncthreads();
    if ((w >> 1) == p) {
      int rbase = (w & 1) * 32;
#pragma unroll
      for (int i = 0; i < 2; i++)
#pragma unroll
        for (int ks = 0; ks < 4; ks++)
          qf[i][ks] = *(const short8*)&Ks[(rbase + i * 16 + lrow) * KS_STR + ks * 32 + lk8 * 8];
    }
  }

  f32x4 acc[2][8];
  float m_i[2][4], l_i[2][4];
#pragma unroll
  for (int i = 0; i < 2; i++) {
#pragma unroll
    for (int n = 0; n < 8; n++) acc[i][n] = (f32x4){0.f, 0.f, 0.f, 0.f};
#pragma unroll
    for (int r = 0; r < 4; r++) { m_i[i][r] = -1e30f; l_i[i][r] = 0.f; }
  }

  const int nkt = qb / AK + 2;
  for (int kt = 0; kt < nkt; kt++) {
    const int kb = kt * AK;
    __syncthreads();  // all waves done with previous Ks/Vts

    // Stage K tile (64 keys x 128 dims)
#pragma unroll
    for (int i = 0; i < 4; i++) {
      int c = tid + i * 256;
      int r = c >> 4, ch = c & 15;
      *(short8*)&Ks[r * KS_STR + ch * 8] =
          *(const short8*)&Kb[(size_t)(kb + r) * 1024 + kvh * 128 + ch * 8];
    }
    // Stage V^T tile (128 dims x 64 keys)
#pragma unroll
    for (int i = 0; i < 4; i++) {
      int c = tid + i * 256;
      int r = c >> 3, ch = c & 7;
      *(short8*)&Vts[r * VT_STR + ch * 8] =
          *(const short8*)&Vt[(size_t)(kvh * 128 + r) * S_LEN + kb + ch * 8];
    }
    __syncthreads();

    // ---- S = Q K^T : 2 row-tiles x 4 col-tiles, 4 k-steps ----
    f32x4 s[2][4];
#pragma unroll
    for (int i = 0; i < 2; i++)
#pragma unroll
      for (int n = 0; n < 4; n++) s[i][n] = (f32x4){0.f, 0.f, 0.f, 0.f};

#pragma unroll
    for (int ks = 0; ks < 4; ks++) {
      short8 bf[4];
#pragma unroll
      for (int n = 0; n < 4; n++)
        bf[n] = *(const short8*)&Ks[(n * 16 + lrow) * KS_STR + ks * 32 + lk8 * 8];
#pragma unroll
      for (int i = 0; i < 2; i++)
#pragma unroll
        for (int n = 0; n < 4; n++)
          s[i][n] = __builtin_amdgcn_mfma_f32_16x16x32_bf16(qf[i][ks], bf[n], s[i][n], 0, 0, 0);
    }

    // ---- Causal mask (only tiles at/after the diagonal) ----
    if (kb + AK > qb) {
#pragma unroll
      for (int i = 0; i < 2; i++) {
        int rowb = qb + w * 32 + i * 16 + lk8 * 4;
#pragma unroll
        for (int n = 0; n < 4; n++) {
          int col = kb + n * 16 + lrow;
#pragma unroll
          for (int r = 0; r < 4; r++)
            if (col > rowb + r) s[i][n][r] = -1e30f;
        }
      }
    }

    // ---- Online softmax (exp2 domain; stats across 16-lane col groups) ----
#pragma unroll
    for (int i = 0; i < 2; i++) {
#pragma unroll
      for (int r = 0; r < 4; r++) {
        float mx = fmaxf(fmaxf(s[i][0][r], s[i][1][r]), fmaxf(s[i][2][r], s[i][3][r]));
        mx = fmaxf(mx, __shfl_xor(mx, 1, 64));
        mx = fmaxf(mx, __shfl_xor(mx, 2, 64));
        mx = fmaxf(mx, __shfl_xor(mx, 4, 64));
        mx = fmaxf(mx, __shfl_xor(mx, 8, 64));
        float mn = fmaxf(m_i[i][r], mx);
        float al = exp2f(m_i[i][r] - mn);
        m_i[i][r] = mn;
        float ls = 0.f;
#pragma unroll
        for (int n = 0; n < 4; n++) {
          float e = exp2f(s[i][n][r] - mn);
          s[i][n][r] = e;
          ls += e;
        }
        ls += __shfl_xor(ls, 1, 64);
        ls += __shfl_xor(ls, 2, 64);
        ls += __shfl_xor(ls, 4, 64);
        ls += __shfl_xor(ls, 8, 64);
        l_i[i][r] = l_i[i][r] * al + ls;
#pragma unroll
        for (int n = 0; n < 8; n++) acc[i][n][r] *= al;
      }
    }

    // ---- P -> LDS (wave-private rows; intra-wave round trip, no barrier) ----
#pragma unroll
    for (int i = 0; i < 2; i++)
#pragma unroll
      for (int n = 0; n < 4; n++)
#pragma unroll
        for (int r = 0; r < 4; r++)
          Ps[(w * 32 + i * 16 + lk8 * 4 + r) * PS_STR + n * 16 + lrow] = f2bf(s[i][n][r]);

    short8 pf[2][2];
#pragma unroll
    for (int i = 0; i < 2; i++)
#pragma unroll
      for (int ks2 = 0; ks2 < 2; ks2++)
        pf[i][ks2] = *(const short8*)&Ps[(w * 32 + i * 16 + lrow) * PS_STR + ks2 * 32 + lk8 * 8];

    // ---- O += P V : 2 row-tiles x 8 dim-tiles, 2 k-steps ----
#pragma unroll
    for (int ks2 = 0; ks2 < 2; ks2++)
#pragma unroll
      for (int n = 0; n < 8; n++) {
        short8 vf = *(const short8*)&Vts[(n * 16 + lrow) * VT_STR + ks2 * 32 + lk8 * 8];
#pragma unroll
        for (int i = 0; i < 2; i++)
          acc[i][n] = __builtin_amdgcn_mfma_f32_16x16x32_bf16(pf[i][ks2], vf, acc[i][n], 0, 0, 0);
      }
  }

  // ---- Epilogue: normalize, bf16 store ----
#pragma unroll
  for (int i = 0; i < 2; i++) {
    float inv[4];
#pragma unroll
    for (int r = 0; r < 4; r++) inv[r] = 1.0f / l_i[i][r];
#pragma unroll
    for (int n = 0; n < 8; n++)
#pragma unroll
      for (int r = 0; r < 4; r++) {
        int row = qb + w * 32 + i * 16 + lk8 * 4 + r;
        Ob[(size_t)row * 4096 + h * 128 + n * 16 + lrow] = f2bf(acc[i][n][r] * inv[r]);
      }
  }
}

// ---------------------------------------------------------------------------
extern "C" void kernel_launch(void* const* d_in, const int* in_sizes, int n_in,
                              void* d_out, int out_size, void* d_ws, size_t ws_size,
                              hipStream_t stream) {
  const float* X  = (const float*)d_in[0];
  const float* Wq = (const float*)d_in[1];
  const float* Wk = (const float*)d_in[2];
  const float* Wv = (const float*)d_in[3];
  const float* Wo = (const float*)d_in[4];
  float* out = (float*)d_out;

  // Workspace (bf16 buffers). Ob aliases Xb, Wob aliases Wqb (both dead
  // after gemm_qkv). Total ~97 MB.
  char* p = (char*)d_ws;
  unsigned short* Qb  = (unsigned short*)p; p += (size_t)S_LEN * 4096 * 2;
  unsigned short* Kb  = (unsigned short*)p; p += (size_t)S_LEN * 1024 * 2;
  unsigned short* Vb  = (unsigned short*)p; p += (size_t)S_LEN * 1024 * 2;
  unsigned short* Vt  = (unsigned short*)p; p += (size_t)1024 * S_LEN * 2;
  unsigned short* Xb  = (unsigned short*)p; p += (size_t)S_LEN * 4096 * 2;
  unsigned short* Wqb = (unsigned short*)p; p += (size_t)4096 * 4096 * 2;
  unsigned short* Wkb = (unsigned short*)p; p += (size_t)1024 * 4096 * 2;
  unsigned short* Wvb = (unsigned short*)p; p += (size_t)1024 * 4096 * 2;
  unsigned short* Ob  = Xb;
  unsigned short* Wob = Wqb;

  // 1. fp32 -> bf16
  conv_bf16<<<(S_LEN * 4096 / 4 + 255) / 256, 256, 0, stream>>>(X, Xb, S_LEN * 4096);
  conv_bf16<<<(4096 * 4096 / 4 + 255) / 256, 256, 0, stream>>>(Wq, Wqb, 4096 * 4096);
  conv_bf16<<<(1024 * 4096 / 4 + 255) / 256, 256, 0, stream>>>(Wk, Wkb, 1024 * 4096);
  conv_bf16<<<(1024 * 4096 / 4 + 255) / 256, 256, 0, stream>>>(Wv, Wvb, 1024 * 4096);

  // 2. Fused QKV projection -> bf16
  gemm_qkv<<<dim3(6144 / 128, S_LEN / 128), 256, 0, stream>>>(Xb, Wqb, Wkb, Wvb, Qb, Kb, Vb);

  // 3. RoPE in-place (Q pre-scaled into exp2 domain)
  int rope_threads = S_LEN * (N_HEADS + N_KV) * 64;
  rope_kernel<<<rope_threads / 256, 256, 0, stream>>>(Qb, Kb);

  // 4. V transpose for MFMA B-operand layout
  transp_v<<<dim3(S_LEN / 64, 1024 / 64), 256, 0, stream>>>(Vb, Vt);

  // 5. Convert Wo (into Wqb space)
  conv_bf16<<<(4096 * 4096 / 4 + 255) / 256, 256, 0, stream>>>(Wo, Wob, 4096 * 4096);

  // 6. MFMA flash attention -> bf16 (into Xb space)
  attn_mfma<<<(S_LEN / AQ) * N_HEADS, 256, 0, stream>>>(Qb, Kb, Vt, Ob);

  // 7. Output projection
  gemm_out<<<dim3(4096 / 128, S_LEN / 128), 256, 0, stream>>>(Ob, Wob, out);
}